// Round 1
// baseline (538.720 us; speedup 1.0000x reference)
//
#include <hip/hip_runtime.h>

#define B_   2
#define S_   2048
#define D_   2048
#define HQ_  16
#define HKV_ 4
#define HD_  128

typedef __attribute__((ext_vector_type(4))) float f32x4;
typedef __attribute__((ext_vector_type(4))) short s16x4;
typedef __attribute__((ext_vector_type(8))) short s16x8;

static __device__ __forceinline__ ushort f2bf(float f) {
  uint32_t u = __float_as_uint(f);
  u += 0x7fffu + ((u >> 16) & 1u);   // RNE
  return (ushort)(u >> 16);
}

static __device__ __forceinline__ s16x8 mk8(s16x4 lo, s16x4 hi) {
  s16x8 r;
  r[0] = lo[0]; r[1] = lo[1]; r[2] = lo[2]; r[3] = lo[3];
  r[4] = hi[0]; r[5] = hi[1]; r[6] = hi[2]; r[7] = hi[3];
  return r;
}

// ---------------- fp32 -> bf16 cast ----------------
__global__ void cast_kernel(const float* __restrict__ in, ushort* __restrict__ out, int n) {
  int i = (blockIdx.x * blockDim.x + threadIdx.x) * 4;
  if (i + 3 < n) {
    float4 v = *(const float4*)(in + i);
    *(ushort4*)(out + i) = make_ushort4(f2bf(v.x), f2bf(v.y), f2bf(v.z), f2bf(v.w));
  }
}

// ---------------- GEMM: C[M][N] (f32) = A[M][K] * B[N][K]^T (both bf16 row-major) ----------------
// 128x128 tile, BK=64, 4 waves each 64x64 (4x4 grid of 16x16x32 mfma frags).
__global__ __launch_bounds__(256) void gemm_nt_bf16(const ushort* __restrict__ A,
                                                    const ushort* __restrict__ Bm,
                                                    float* __restrict__ C,
                                                    int M, int N, int K) {
  __shared__ ushort As[128][72];
  __shared__ ushort Bs[128][72];
  const int tid  = threadIdx.x;
  const int lane = tid & 63;
  const int wave = tid >> 6;
  const int lrow = lane & 15, lgrp = lane >> 4;
  const int wm = (wave >> 1) * 64, wn = (wave & 1) * 64;
  const int brow = blockIdx.y * 128, bcol = blockIdx.x * 128;

  f32x4 acc[4][4];
#pragma unroll
  for (int i = 0; i < 4; ++i)
#pragma unroll
    for (int j = 0; j < 4; ++j) acc[i][j] = (f32x4){0.f, 0.f, 0.f, 0.f};

  const int r = tid >> 1, half = (tid & 1) * 32;
  const ushort* Ag = A + (size_t)(brow + r) * K + half;
  const ushort* Bg = Bm + (size_t)(bcol + r) * K + half;

  for (int k0 = 0; k0 < K; k0 += 64) {
    const s16x8* a8 = (const s16x8*)(Ag + k0);
    const s16x8* b8 = (const s16x8*)(Bg + k0);
    s16x8* da = (s16x8*)&As[r][half];
    s16x8* db = (s16x8*)&Bs[r][half];
#pragma unroll
    for (int q = 0; q < 4; ++q) { da[q] = a8[q]; db[q] = b8[q]; }
    __syncthreads();
#pragma unroll
    for (int kc = 0; kc < 2; ++kc) {
      const int ko = kc * 32 + lgrp * 4;
      s16x8 aF[4], bF[4];
#pragma unroll
      for (int mt = 0; mt < 4; ++mt)
        aF[mt] = mk8(*(const s16x4*)&As[wm + mt * 16 + lrow][ko],
                     *(const s16x4*)&As[wm + mt * 16 + lrow][ko + 16]);
#pragma unroll
      for (int nt = 0; nt < 4; ++nt)
        bF[nt] = mk8(*(const s16x4*)&Bs[wn + nt * 16 + lrow][ko],
                     *(const s16x4*)&Bs[wn + nt * 16 + lrow][ko + 16]);
#pragma unroll
      for (int mt = 0; mt < 4; ++mt)
#pragma unroll
        for (int nt = 0; nt < 4; ++nt)
          acc[mt][nt] = __builtin_amdgcn_mfma_f32_16x16x32_bf16(aF[mt], bF[nt], acc[mt][nt], 0, 0, 0);
    }
    __syncthreads();
  }
#pragma unroll
  for (int mt = 0; mt < 4; ++mt) {
#pragma unroll
    for (int nt = 0; nt < 4; ++nt) {
      const int row = brow + wm + mt * 16 + lgrp * 4;
      const int col = bcol + wn + nt * 16 + lrow;
#pragma unroll
      for (int rr = 0; rr < 4; ++rr)
        C[(size_t)(row + rr) * N + col] = acc[mt][nt][rr];
    }
  }
}

// ---------------- RoPE on Q and K (reads fused QKV f32, writes bf16 head-major) ----------------
__global__ void rope_qk(const float* __restrict__ qkv, ushort* __restrict__ Qb, ushort* __restrict__ Kb) {
  int idx = blockIdx.x * 256 + threadIdx.x;      // ((b*S+s)*20 + h2)*64 + i
  int i  = idx & 63;
  int t  = idx >> 6;
  int h2 = t % 20;
  int t2 = t / 20;
  int s  = t2 & (S_ - 1);
  int b  = t2 >> 11;
  float inv = exp2f(-(float)i * 0.20762050594046832f);  // log2(10000)/64
  float f = (float)s * inv;
  float sn, cs;
  sincosf(f, &sn, &cs);
  size_t row = (size_t)(b * S_ + s) * 3072;
  if (h2 < HQ_) {
    int h = h2;
    float a = qkv[row + h * 128 + i];
    float c2 = qkv[row + h * 128 + i + 64];
    size_t ob = ((size_t)((b * HQ_ + h) * S_ + s)) * 128;
    Qb[ob + i]      = f2bf(a * cs - c2 * sn);
    Qb[ob + i + 64] = f2bf(c2 * cs + a * sn);
  } else {
    int kh = h2 - HQ_;
    float a = qkv[row + 2048 + kh * 128 + i];
    float c2 = qkv[row + 2048 + kh * 128 + i + 64];
    size_t ob = ((size_t)((b * HKV_ + kh) * S_ + s)) * 128;
    Kb[ob + i]      = f2bf(a * cs - c2 * sn);
    Kb[ob + i + 64] = f2bf(c2 * cs + a * sn);
  }
}

// ---------------- V transpose: qkv f32 V-part -> Vt[b][kh][d][s] bf16 ----------------
__global__ __launch_bounds__(256) void v_transpose(const float* __restrict__ qkv, ushort* __restrict__ Vt) {
  __shared__ ushort tile[128][72];
  const int s0 = blockIdx.x * 64;
  const int kh = blockIdx.y;
  const int b  = blockIdx.z;
  for (int idx = threadIdx.x; idx < 64 * 128; idx += 256) {
    int sl = idx >> 7;
    int d  = idx & 127;
    float v = qkv[(size_t)(b * S_ + s0 + sl) * 3072 + 2560 + kh * 128 + d];
    tile[d][sl] = f2bf(v);
  }
  __syncthreads();
  for (int idx = threadIdx.x; idx < 64 * 128; idx += 256) {
    int d  = idx >> 6;
    int sl = idx & 63;
    Vt[((size_t)(b * HKV_ + kh) * 128 + d) * S_ + s0 + sl] = tile[d][sl];
  }
}

// ---------------- Flash attention (causal, GQA) ----------------
// grid (S/64, HQ, B), 256 thr. 4 waves x 16 q-rows. KVBLK=64.
// Swapped QK^T: S^T = K*Q^T so P (in C layout) is directly the A operand of P*V.
__global__ __launch_bounds__(256) void attn_kernel(const ushort* __restrict__ Qb,
                                                   const ushort* __restrict__ Kb,
                                                   const ushort* __restrict__ Vt,
                                                   ushort* __restrict__ Ao) {
  __shared__ ushort Ks[64][136];
  __shared__ ushort Vts[128][72];
  const int qb = blockIdx.x;
  const int h  = blockIdx.y;
  const int b  = blockIdx.z;
  const int kh = h >> 2;
  const int tid = threadIdx.x, lane = tid & 63, wave = tid >> 6;
  const int lrow = lane & 15, lgrp = lane >> 4;
  const int q0 = qb * 64;
  const float NEGINF = -3.0e38f;

  // stage Q tile (reuse Ks buffer)
  {
    const int r = tid >> 2, qd = (tid & 3) * 32;
    const s16x8* s8 = (const s16x8*)(Qb + (((size_t)(b * HQ_ + h)) * S_ + q0 + r) * HD_ + qd);
    s16x8* dst = (s16x8*)&Ks[r][qd];
#pragma unroll
    for (int q = 0; q < 4; ++q) dst[q] = s8[q];
  }
  __syncthreads();
  s16x8 qF[4];
#pragma unroll
  for (int c = 0; c < 4; ++c)
    qF[c] = mk8(*(const s16x4*)&Ks[wave * 16 + lrow][c * 32 + lgrp * 4],
                *(const s16x4*)&Ks[wave * 16 + lrow][c * 32 + lgrp * 4 + 16]);
  __syncthreads();

  float m_run = NEGINF, l_run = 0.f;
  f32x4 o[8];
#pragma unroll
  for (int dt = 0; dt < 8; ++dt) o[dt] = (f32x4){0.f, 0.f, 0.f, 0.f};
  const float scale = 0.08838834764831845f;  // 1/sqrt(128)
  const int qg = q0 + wave * 16 + lrow;

  for (int kt = 0; kt <= qb; ++kt) {
    {  // stage K tile
      const int r = tid >> 2, qd = (tid & 3) * 32;
      const s16x8* s8 = (const s16x8*)(Kb + (((size_t)(b * HKV_ + kh)) * S_ + kt * 64 + r) * HD_ + qd);
      s16x8* dst = (s16x8*)&Ks[r][qd];
#pragma unroll
      for (int q = 0; q < 4; ++q) dst[q] = s8[q];
    }
    {  // stage Vt tile [128 d][64 k]
      const int d = tid >> 1, sh = (tid & 1) * 32;
      const s16x8* s8 = (const s16x8*)(Vt + ((size_t)(b * HKV_ + kh) * 128 + d) * S_ + kt * 64 + sh);
      s16x8* dst = (s16x8*)&Vts[d][sh];
#pragma unroll
      for (int q = 0; q < 4; ++q) dst[q] = s8[q];
    }
    __syncthreads();

    // S^T = K (64x128) * Q^T (128x16): 4 halves of 16 k-rows
    f32x4 sF[4];
#pragma unroll
    for (int hh = 0; hh < 4; ++hh) {
      f32x4 a = (f32x4){0.f, 0.f, 0.f, 0.f};
#pragma unroll
      for (int c = 0; c < 4; ++c) {
        s16x8 kA = mk8(*(const s16x4*)&Ks[hh * 16 + lrow][c * 32 + lgrp * 4],
                       *(const s16x4*)&Ks[hh * 16 + lrow][c * 32 + lgrp * 4 + 16]);
        a = __builtin_amdgcn_mfma_f32_16x16x32_bf16(kA, qF[c], a, 0, 0, 0);
      }
      sF[hh] = a;
    }

    // softmax (lane owns q = qg, holds 16 k-values)
    float p[16];
    float tmax = NEGINF;
#pragma unroll
    for (int hh = 0; hh < 4; ++hh)
#pragma unroll
      for (int rr = 0; rr < 4; ++rr) {
        int kg = kt * 64 + hh * 16 + lgrp * 4 + rr;
        float s = sF[hh][rr] * scale;
        s = (kg <= qg) ? s : NEGINF;
        p[hh * 4 + rr] = s;
        tmax = fmaxf(tmax, s);
      }
    tmax = fmaxf(tmax, __shfl_xor(tmax, 16, 64));
    tmax = fmaxf(tmax, __shfl_xor(tmax, 32, 64));
    float m_new = fmaxf(m_run, tmax);
    float alpha = expf(m_run - m_new);
    float psum = 0.f;
#pragma unroll
    for (int i = 0; i < 16; ++i) {
      p[i] = expf(p[i] - m_new);
      psum += p[i];
    }
    psum += __shfl_xor(psum, 16, 64);
    psum += __shfl_xor(psum, 32, 64);
    l_run = l_run * alpha + psum;
    m_run = m_new;

    float alphaR[4];
#pragma unroll
    for (int rr = 0; rr < 4; ++rr) alphaR[rr] = __shfl(alpha, lgrp * 4 + rr, 64);
#pragma unroll
    for (int dt = 0; dt < 8; ++dt)
#pragma unroll
      for (int rr = 0; rr < 4; ++rr) o[dt][rr] *= alphaR[rr];

    // pack P to bf16 A-frags (k 0..31 and 32..63)
    s16x8 pa0, pa1;
#pragma unroll
    for (int j = 0; j < 8; ++j) { pa0[j] = (short)f2bf(p[j]); pa1[j] = (short)f2bf(p[8 + j]); }

#pragma unroll
    for (int dt = 0; dt < 8; ++dt) {
      s16x8 v0 = mk8(*(const s16x4*)&Vts[dt * 16 + lrow][lgrp * 4],
                     *(const s16x4*)&Vts[dt * 16 + lrow][lgrp * 4 + 16]);
      s16x8 v1 = mk8(*(const s16x4*)&Vts[dt * 16 + lrow][32 + lgrp * 4],
                     *(const s16x4*)&Vts[dt * 16 + lrow][32 + lgrp * 4 + 16]);
      o[dt] = __builtin_amdgcn_mfma_f32_16x16x32_bf16(pa0, v0, o[dt], 0, 0, 0);
      o[dt] = __builtin_amdgcn_mfma_f32_16x16x32_bf16(pa1, v1, o[dt], 0, 0, 0);
    }
    __syncthreads();
  }

  float lR[4];
#pragma unroll
  for (int rr = 0; rr < 4; ++rr) lR[rr] = 1.f / __shfl(l_run, lgrp * 4 + rr, 64);
#pragma unroll
  for (int dt = 0; dt < 8; ++dt)
#pragma unroll
    for (int rr = 0; rr < 4; ++rr) {
      int s = q0 + wave * 16 + lgrp * 4 + rr;
      Ao[(size_t)(b * S_ + s) * D_ + h * HD_ + dt * 16 + lrow] = f2bf(o[dt][rr] * lR[rr]);
    }
}

extern "C" void kernel_launch(void* const* d_in, const int* in_sizes, int n_in,
                              void* d_out, int out_size, void* d_ws, size_t ws_size,
                              hipStream_t stream) {
  const float* x  = (const float*)d_in[0];
  const float* wq = (const float*)d_in[1];
  const float* wk = (const float*)d_in[2];
  const float* wv = (const float*)d_in[3];
  const float* wo = (const float*)d_in[4];
  float* out = (float*)d_out;
  char* ws = (char*)d_ws;

  ushort* xb    = (ushort*)(ws);                  // 16,777,216 B
  ushort* wqkvb = (ushort*)(ws + 16777216);       // 12,582,912 B
  ushort* wob   = (ushort*)(ws + 29360128);       //  8,388,608 B
  float*  qkvf  = (float*) (ws + 37748736);       // 50,331,648 B
  ushort* Qb    = (ushort*)(ws + 88080384);       // 16,777,216 B
  ushort* Kb    = (ushort*)(ws + 104857600);      //  4,194,304 B
  ushort* Vt    = (ushort*)(ws + 109051904);      //  4,194,304 B
  ushort* Ao    = (ushort*)(ws + 113246208);      // 16,777,216 B

  cast_kernel<<<8192, 256, 0, stream>>>(x,  xb, 8388608);
  cast_kernel<<<4096, 256, 0, stream>>>(wq, wqkvb, 4194304);
  cast_kernel<<<1024, 256, 0, stream>>>(wk, wqkvb + 4194304, 1048576);
  cast_kernel<<<1024, 256, 0, stream>>>(wv, wqkvb + 5242880, 1048576);
  cast_kernel<<<4096, 256, 0, stream>>>(wo, wob, 4194304);

  gemm_nt_bf16<<<dim3(24, 32), 256, 0, stream>>>(xb, wqkvb, qkvf, 4096, 3072, 2048);
  rope_qk<<<20480, 256, 0, stream>>>(qkvf, Qb, Kb);
  v_transpose<<<dim3(32, 4, 2), 256, 0, stream>>>(qkvf, Vt);
  attn_kernel<<<dim3(32, 16, 2), 256, 0, stream>>>(Qb, Kb, Vt, Ao);
  gemm_nt_bf16<<<dim3(16, 32), 256, 0, stream>>>(Ao, wob, out, 4096, 2048, 2048);
}

// Round 2
// 357.564 us; speedup vs baseline: 1.5066x; 1.5066x over previous
//
#include <hip/hip_runtime.h>

#define B_   2
#define S_   2048
#define D_   2048
#define HQ_  16
#define HKV_ 4
#define HD_  128

typedef __attribute__((ext_vector_type(4))) float f32x4;
typedef __attribute__((ext_vector_type(4))) short s16x4;
typedef __attribute__((ext_vector_type(8))) short s16x8;

static __device__ __forceinline__ ushort f2bf(float f) {
  uint32_t u = __float_as_uint(f);
  u += 0x7fffu + ((u >> 16) & 1u);   // RNE
  return (ushort)(u >> 16);
}

static __device__ __forceinline__ s16x8 mk8(s16x4 lo, s16x4 hi) {
  s16x8 r;
  r[0] = lo[0]; r[1] = lo[1]; r[2] = lo[2]; r[3] = lo[3];
  r[4] = hi[0]; r[5] = hi[1]; r[6] = hi[2]; r[7] = hi[3];
  return r;
}

static __device__ __forceinline__ void gload16(const ushort* g, ushort* l) {
  __builtin_amdgcn_global_load_lds((const __attribute__((address_space(1))) uint32_t*)(g),
                                   (__attribute__((address_space(3))) uint32_t*)(l), 16, 0, 0);
}

// ---------------- fp32 -> bf16 cast ----------------
__global__ void cast_kernel(const float* __restrict__ in, ushort* __restrict__ out, int n) {
  int i = (blockIdx.x * blockDim.x + threadIdx.x) * 4;
  if (i + 3 < n) {
    float4 v = *(const float4*)(in + i);
    *(ushort4*)(out + i) = make_ushort4(f2bf(v.x), f2bf(v.y), f2bf(v.z), f2bf(v.w));
  }
}

// ---------------- GEMM: C[M][N] (f32) = A[M][K] * B[N][K]^T (both bf16 row-major) ----------------
// 128x128 tile, BK=64, m97 structure: global_load_lds width-16 staging into linear LDS,
// XOR-swizzled (pre-swizzled source + swizzled b128 fragment reads), k-permuted frags.
__global__ __launch_bounds__(256) void gemm_nt_bf16(const ushort* __restrict__ A,
                                                    const ushort* __restrict__ Bm,
                                                    float* __restrict__ C,
                                                    int M, int N, int K) {
  __shared__ ushort As[128 * 64];
  __shared__ ushort Bs[128 * 64];
  const int tid  = threadIdx.x;
  const int lane = tid & 63;
  const int wave = tid >> 6;
  const int lrow = lane & 15, lgrp = lane >> 4;
  const int wm = (wave >> 1) * 64, wn = (wave & 1) * 64;
  const int brow = blockIdx.y * 128, bcol = blockIdx.x * 128;

  f32x4 acc[4][4];
#pragma unroll
  for (int i = 0; i < 4; ++i)
#pragma unroll
    for (int j = 0; j < 4; ++j) acc[i][j] = (f32x4){0.f, 0.f, 0.f, 0.f};

  const int r_ = tid >> 3, c16 = tid & 7;
  const ushort* Abase = A + (size_t)brow * K;
  const ushort* Bbase = Bm + (size_t)bcol * K;

  for (int k0 = 0; k0 < K; k0 += 64) {
    // stage: LDS slot (row, c16) <- global chunk (c16 ^ (row&7))  [16B units]
#pragma unroll
    for (int q = 0; q < 4; ++q) {
      const int row = q * 32 + r_;
      const int sc = c16 ^ (row & 7);
      gload16(Abase + (size_t)row * K + k0 + sc * 8, &As[q * 2048 + wave * 512]);
      gload16(Bbase + (size_t)row * K + k0 + sc * 8, &Bs[q * 2048 + wave * 512]);
    }
    __syncthreads();
#pragma unroll
    for (int kc = 0; kc < 2; ++kc) {
      s16x8 aF[4], bF[4];
#pragma unroll
      for (int mt = 0; mt < 4; ++mt) {
        const int row = wm + mt * 16 + lrow;
        aF[mt] = *(const s16x8*)&As[row * 64 + ((kc * 32 + lgrp * 8) ^ ((row & 7) << 3))];
      }
#pragma unroll
      for (int nt = 0; nt < 4; ++nt) {
        const int row = wn + nt * 16 + lrow;
        bF[nt] = *(const s16x8*)&Bs[row * 64 + ((kc * 32 + lgrp * 8) ^ ((row & 7) << 3))];
      }
#pragma unroll
      for (int mt = 0; mt < 4; ++mt)
#pragma unroll
        for (int nt = 0; nt < 4; ++nt)
          acc[mt][nt] = __builtin_amdgcn_mfma_f32_16x16x32_bf16(aF[mt], bF[nt], acc[mt][nt], 0, 0, 0);
    }
    __syncthreads();
  }
#pragma unroll
  for (int mt = 0; mt < 4; ++mt) {
#pragma unroll
    for (int nt = 0; nt < 4; ++nt) {
      const int row = brow + wm + mt * 16 + lgrp * 4;
      const int col = bcol + wn + nt * 16 + lrow;
#pragma unroll
      for (int rr = 0; rr < 4; ++rr)
        C[(size_t)(row + rr) * N + col] = acc[mt][nt][rr];
    }
  }
}

// ---------------- RoPE on Q and K (reads fused QKV f32, writes bf16 head-major) ----------------
__global__ void rope_qk(const float* __restrict__ qkv, ushort* __restrict__ Qb, ushort* __restrict__ Kb) {
  int idx = blockIdx.x * 256 + threadIdx.x;      // ((b*S+s)*20 + h2)*64 + i
  int i  = idx & 63;
  int t  = idx >> 6;
  int h2 = t % 20;
  int t2 = t / 20;
  int s  = t2 & (S_ - 1);
  int b  = t2 >> 11;
  float inv = exp2f(-(float)i * 0.20762050594046832f);  // log2(10000)/64
  float f = (float)s * inv;
  float sn, cs;
  sincosf(f, &sn, &cs);
  size_t row = (size_t)(b * S_ + s) * 3072;
  if (h2 < HQ_) {
    int h = h2;
    float a = qkv[row + h * 128 + i];
    float c2 = qkv[row + h * 128 + i + 64];
    size_t ob = ((size_t)((b * HQ_ + h) * S_ + s)) * 128;
    Qb[ob + i]      = f2bf(a * cs - c2 * sn);
    Qb[ob + i + 64] = f2bf(c2 * cs + a * sn);
  } else {
    int kh = h2 - HQ_;
    float a = qkv[row + 2048 + kh * 128 + i];
    float c2 = qkv[row + 2048 + kh * 128 + i + 64];
    size_t ob = ((size_t)((b * HKV_ + kh) * S_ + s)) * 128;
    Kb[ob + i]      = f2bf(a * cs - c2 * sn);
    Kb[ob + i + 64] = f2bf(c2 * cs + a * sn);
  }
}

// ---------------- V transpose: qkv f32 V-part -> Vt[b][kh][d][s] bf16 ----------------
__global__ __launch_bounds__(256) void v_transpose(const float* __restrict__ qkv, ushort* __restrict__ Vt) {
  __shared__ ushort tile[128][72];
  const int s0 = blockIdx.x * 64;
  const int kh = blockIdx.y;
  const int b  = blockIdx.z;
  for (int idx = threadIdx.x; idx < 64 * 128; idx += 256) {
    int sl = idx >> 7;
    int d  = idx & 127;
    float v = qkv[(size_t)(b * S_ + s0 + sl) * 3072 + 2560 + kh * 128 + d];
    tile[d][sl] = f2bf(v);
  }
  __syncthreads();
  for (int idx = threadIdx.x; idx < 64 * 128; idx += 256) {
    int d  = idx >> 6;
    int sl = idx & 63;
    Vt[((size_t)(b * HKV_ + kh) * 128 + d) * S_ + s0 + sl] = tile[d][sl];
  }
}

// ---------------- Flash attention (causal, GQA) ----------------
// grid (16, HQ, B), 256 thr. Causal pairing: block x handles q-tiles x and 31-x
// (uniform 33 kt-iters per block). 4 waves x 16 q-rows, KVBLK=64.
// Swapped QK^T (S^T = K*Q^T) so softmaxed P in C-layout feeds PV's A operand directly.
// log2-domain softmax (exp2f). XOR-swizzled LDS tiles (byte ^= (row&7)<<4).
__global__ __launch_bounds__(256) void attn_kernel(const ushort* __restrict__ Qb,
                                                   const ushort* __restrict__ Kb,
                                                   const ushort* __restrict__ Vt,
                                                   ushort* __restrict__ Ao) {
  __shared__ ushort Qs[64 * 128];
  __shared__ ushort Ks[64 * 128];
  __shared__ ushort Vts[128 * 64];
  const int h  = blockIdx.y;
  const int b  = blockIdx.z;
  const int kh = h >> 2;
  const int tid = threadIdx.x, lane = tid & 63, wave = tid >> 6;
  const int lrow = lane & 15, lgrp = lane >> 4;
  const int sw = (lrow & 7) << 3;          // ushort-unit XOR swizzle for rows ≡ lrow (mod 8)
  const float NEGINF = -3.0e38f;
  const float SCL2 = 0.12751744717f;       // (1/sqrt(128)) * log2(e)

#pragma unroll 1
  for (int hf = 0; hf < 2; ++hf) {
    const int qt = hf ? (31 - (int)blockIdx.x) : (int)blockIdx.x;
    const int q0 = qt * 64;

    {  // stage Q tile [64 rows][128 d], swizzled
      const int r = tid >> 2;
      const int swr = (r & 7) << 3;
      const ushort* src = Qb + (((size_t)(b * HQ_ + h)) * S_ + q0 + r) * HD_ + (tid & 3) * 32;
#pragma unroll
      for (int q = 0; q < 4; ++q) {
        const int u = (tid & 3) * 32 + q * 8;
        *(s16x8*)&Qs[r * 128 + (u ^ swr)] = *(const s16x8*)(src + q * 8);
      }
    }
    __syncthreads();
    s16x8 qF[4];
#pragma unroll
    for (int c = 0; c < 4; ++c)
      qF[c] = *(const s16x8*)&Qs[(wave * 16 + lrow) * 128 + ((c * 32 + lgrp * 8) ^ sw)];

    float m_run = NEGINF, l_run = 0.f;
    f32x4 o[8];
#pragma unroll
    for (int dt = 0; dt < 8; ++dt) o[dt] = (f32x4){0.f, 0.f, 0.f, 0.f};
    const int qg = q0 + wave * 16 + lrow;

    for (int kt = 0; kt <= qt; ++kt) {
      {  // stage K tile [64 k][128 d], swizzled
        const int r = tid >> 2;
        const int swr = (r & 7) << 3;
        const ushort* src = Kb + (((size_t)(b * HKV_ + kh)) * S_ + kt * 64 + r) * HD_ + (tid & 3) * 32;
#pragma unroll
        for (int q = 0; q < 4; ++q) {
          const int u = (tid & 3) * 32 + q * 8;
          *(s16x8*)&Ks[r * 128 + (u ^ swr)] = *(const s16x8*)(src + q * 8);
        }
      }
      {  // stage V^T tile [128 d][64 k], swizzled
        const int r = tid >> 1;
        const int swr = (r & 7) << 3;
        const ushort* src = Vt + ((size_t)(b * HKV_ + kh) * 128 + r) * S_ + kt * 64 + (tid & 1) * 32;
#pragma unroll
        for (int q = 0; q < 4; ++q) {
          const int u = (tid & 1) * 32 + q * 8;
          *(s16x8*)&Vts[r * 64 + (u ^ swr)] = *(const s16x8*)(src + q * 8);
        }
      }
      __syncthreads();

      // S^T = K (64x128) * Q^T: 4 blocks of 16 k-rows; contiguous k-permuted frags
      f32x4 sF[4];
#pragma unroll
      for (int hh = 0; hh < 4; ++hh) {
        f32x4 a = (f32x4){0.f, 0.f, 0.f, 0.f};
#pragma unroll
        for (int c = 0; c < 4; ++c) {
          const s16x8 kA = *(const s16x8*)&Ks[(hh * 16 + lrow) * 128 + ((c * 32 + lgrp * 8) ^ sw)];
          a = __builtin_amdgcn_mfma_f32_16x16x32_bf16(kA, qF[c], a, 0, 0, 0);
        }
        sF[hh] = a;
      }

      // softmax in log2 domain; mask only on the diagonal tile
      float p[16];
      float tmax = NEGINF;
      if (kt == qt) {
#pragma unroll
        for (int hh = 0; hh < 4; ++hh)
#pragma unroll
          for (int rr = 0; rr < 4; ++rr) {
            const int kg = kt * 64 + hh * 16 + lgrp * 4 + rr;
            const float s = (kg <= qg) ? sF[hh][rr] * SCL2 : NEGINF;
            p[hh * 4 + rr] = s;
            tmax = fmaxf(tmax, s);
          }
      } else {
#pragma unroll
        for (int hh = 0; hh < 4; ++hh)
#pragma unroll
          for (int rr = 0; rr < 4; ++rr) {
            const float s = sF[hh][rr] * SCL2;
            p[hh * 4 + rr] = s;
            tmax = fmaxf(tmax, s);
          }
      }
      tmax = fmaxf(tmax, __shfl_xor(tmax, 16, 64));
      tmax = fmaxf(tmax, __shfl_xor(tmax, 32, 64));
      const float m_new = fmaxf(m_run, tmax);
      const float alpha = exp2f(m_run - m_new);
      float psum = 0.f;
#pragma unroll
      for (int i = 0; i < 16; ++i) {
        p[i] = exp2f(p[i] - m_new);
        psum += p[i];
      }
      psum += __shfl_xor(psum, 16, 64);
      psum += __shfl_xor(psum, 32, 64);
      l_run = l_run * alpha + psum;
      m_run = m_new;

      float alphaR[4];
#pragma unroll
      for (int rr = 0; rr < 4; ++rr) alphaR[rr] = __shfl(alpha, lgrp * 4 + rr, 64);
#pragma unroll
      for (int dt = 0; dt < 8; ++dt)
#pragma unroll
        for (int rr = 0; rr < 4; ++rr) o[dt][rr] *= alphaR[rr];

      // pack P to bf16 A-frags (k 0..31 and 32..63); hardware k-slots fixed
      s16x8 pa0, pa1;
#pragma unroll
      for (int j = 0; j < 8; ++j) { pa0[j] = (short)f2bf(p[j]); pa1[j] = (short)f2bf(p[8 + j]); }

#pragma unroll
      for (int dt = 0; dt < 8; ++dt) {
        const int vr = dt * 16 + lrow;
        s16x8 v0 = mk8(*(const s16x4*)&Vts[vr * 64 + ((lgrp * 4) ^ sw)],
                       *(const s16x4*)&Vts[vr * 64 + ((lgrp * 4 + 16) ^ sw)]);
        s16x8 v1 = mk8(*(const s16x4*)&Vts[vr * 64 + ((32 + lgrp * 4) ^ sw)],
                       *(const s16x4*)&Vts[vr * 64 + ((32 + lgrp * 4 + 16) ^ sw)]);
        o[dt] = __builtin_amdgcn_mfma_f32_16x16x32_bf16(pa0, v0, o[dt], 0, 0, 0);
        o[dt] = __builtin_amdgcn_mfma_f32_16x16x32_bf16(pa1, v1, o[dt], 0, 0, 0);
      }
      __syncthreads();
    }

    float lR[4];
#pragma unroll
    for (int rr = 0; rr < 4; ++rr) lR[rr] = 1.f / __shfl(l_run, lgrp * 4 + rr, 64);
#pragma unroll
    for (int dt = 0; dt < 8; ++dt)
#pragma unroll
      for (int rr = 0; rr < 4; ++rr) {
        const int s = q0 + wave * 16 + lgrp * 4 + rr;
        Ao[(size_t)(b * S_ + s) * D_ + h * HD_ + dt * 16 + lrow] = f2bf(o[dt][rr] * lR[rr]);
      }
  }
}

extern "C" void kernel_launch(void* const* d_in, const int* in_sizes, int n_in,
                              void* d_out, int out_size, void* d_ws, size_t ws_size,
                              hipStream_t stream) {
  const float* x  = (const float*)d_in[0];
  const float* wq = (const float*)d_in[1];
  const float* wk = (const float*)d_in[2];
  const float* wv = (const float*)d_in[3];
  const float* wo = (const float*)d_in[4];
  float* out = (float*)d_out;
  char* ws = (char*)d_ws;

  ushort* xb    = (ushort*)(ws);                  // 16,777,216 B
  ushort* wqkvb = (ushort*)(ws + 16777216);       // 12,582,912 B
  ushort* wob   = (ushort*)(ws + 29360128);       //  8,388,608 B
  float*  qkvf  = (float*) (ws + 37748736);       // 50,331,648 B
  ushort* Qb    = (ushort*)(ws + 88080384);       // 16,777,216 B
  ushort* Kb    = (ushort*)(ws + 104857600);      //  4,194,304 B
  ushort* Vt    = (ushort*)(ws + 109051904);      //  4,194,304 B
  ushort* Ao    = (ushort*)(ws + 113246208);      // 16,777,216 B

  cast_kernel<<<8192, 256, 0, stream>>>(x,  xb, 8388608);
  cast_kernel<<<4096, 256, 0, stream>>>(wq, wqkvb, 4194304);
  cast_kernel<<<1024, 256, 0, stream>>>(wk, wqkvb + 4194304, 1048576);
  cast_kernel<<<1024, 256, 0, stream>>>(wv, wqkvb + 5242880, 1048576);
  cast_kernel<<<4096, 256, 0, stream>>>(wo, wob, 4194304);

  gemm_nt_bf16<<<dim3(24, 32), 256, 0, stream>>>(xb, wqkvb, qkvf, 4096, 3072, 2048);
  rope_qk<<<20480, 256, 0, stream>>>(qkvf, Qb, Kb);
  v_transpose<<<dim3(32, 4, 2), 256, 0, stream>>>(qkvf, Vt);
  attn_kernel<<<dim3(16, 16, 2), 256, 0, stream>>>(Qb, Kb, Vt, Ao);
  gemm_nt_bf16<<<dim3(16, 32), 256, 0, stream>>>(Ao, wob, out, 4096, 2048, 2048);
}

// Round 3
// 347.794 us; speedup vs baseline: 1.5490x; 1.0281x over previous
//
#include <hip/hip_runtime.h>

#define B_   2
#define S_   2048
#define D_   2048
#define HQ_  16
#define HKV_ 4
#define HD_  128

typedef __attribute__((ext_vector_type(4))) float f32x4;
typedef __attribute__((ext_vector_type(16))) float f32x16;
typedef __attribute__((ext_vector_type(4))) short s16x4;
typedef __attribute__((ext_vector_type(8))) short s16x8;

static __device__ __forceinline__ ushort f2bf(float f) {
  uint32_t u = __float_as_uint(f);
  u += 0x7fffu + ((u >> 16) & 1u);   // RNE
  return (ushort)(u >> 16);
}

static __device__ __forceinline__ void gload16(const ushort* g, ushort* l) {
  __builtin_amdgcn_global_load_lds((const __attribute__((address_space(1))) uint32_t*)(g),
                                   (__attribute__((address_space(3))) uint32_t*)(l), 16, 0, 0);
}

// ---------------- fp32 -> bf16 cast ----------------
__global__ void cast_kernel(const float* __restrict__ in, ushort* __restrict__ out, int n) {
  int i = (blockIdx.x * blockDim.x + threadIdx.x) * 4;
  if (i + 3 < n) {
    float4 v = *(const float4*)(in + i);
    *(ushort4*)(out + i) = make_ushort4(f2bf(v.x), f2bf(v.y), f2bf(v.z), f2bf(v.w));
  }
}

// ---------------- GEMM: C[M][N] (f32) = A[M][K] * B[N][K]^T (both bf16 row-major) ----------------
// 128x128 tile, BK=64, m97 structure + bijective XCD swizzle (1D grid).
__global__ __launch_bounds__(256) void gemm_nt_bf16(const ushort* __restrict__ A,
                                                    const ushort* __restrict__ Bm,
                                                    float* __restrict__ C,
                                                    int M, int N, int K, int nbx) {
  __shared__ ushort As[128 * 64];
  __shared__ ushort Bs[128 * 64];
  const int nwg = gridDim.x;
  const int per = nwg >> 3;
  const int id = blockIdx.x;
  const int wg = (id & 7) * per + (id >> 3);
  const int bx = wg % nbx, by = wg / nbx;
  const int tid  = threadIdx.x;
  const int lane = tid & 63;
  const int wave = tid >> 6;
  const int lrow = lane & 15, lgrp = lane >> 4;
  const int wm = (wave >> 1) * 64, wn = (wave & 1) * 64;
  const int brow = by * 128, bcol = bx * 128;

  f32x4 acc[4][4];
#pragma unroll
  for (int i = 0; i < 4; ++i)
#pragma unroll
    for (int j = 0; j < 4; ++j) acc[i][j] = (f32x4){0.f, 0.f, 0.f, 0.f};

  const int r_ = tid >> 3, c16 = tid & 7;
  const ushort* Abase = A + (size_t)brow * K;
  const ushort* Bbase = Bm + (size_t)bcol * K;

  for (int k0 = 0; k0 < K; k0 += 64) {
#pragma unroll
    for (int q = 0; q < 4; ++q) {
      const int row = q * 32 + r_;
      const int sc = c16 ^ (row & 7);
      gload16(Abase + (size_t)row * K + k0 + sc * 8, &As[q * 2048 + wave * 512]);
      gload16(Bbase + (size_t)row * K + k0 + sc * 8, &Bs[q * 2048 + wave * 512]);
    }
    __syncthreads();
#pragma unroll
    for (int kc = 0; kc < 2; ++kc) {
      s16x8 aF[4], bF[4];
#pragma unroll
      for (int mt = 0; mt < 4; ++mt) {
        const int row = wm + mt * 16 + lrow;
        aF[mt] = *(const s16x8*)&As[row * 64 + ((kc * 32 + lgrp * 8) ^ ((row & 7) << 3))];
      }
#pragma unroll
      for (int nt = 0; nt < 4; ++nt) {
        const int row = wn + nt * 16 + lrow;
        bF[nt] = *(const s16x8*)&Bs[row * 64 + ((kc * 32 + lgrp * 8) ^ ((row & 7) << 3))];
      }
#pragma unroll
      for (int mt = 0; mt < 4; ++mt)
#pragma unroll
        for (int nt = 0; nt < 4; ++nt)
          acc[mt][nt] = __builtin_amdgcn_mfma_f32_16x16x32_bf16(aF[mt], bF[nt], acc[mt][nt], 0, 0, 0);
    }
    __syncthreads();
  }
#pragma unroll
  for (int mt = 0; mt < 4; ++mt) {
#pragma unroll
    for (int nt = 0; nt < 4; ++nt) {
      const int row = brow + wm + mt * 16 + lgrp * 4;
      const int col = bcol + wn + nt * 16 + lrow;
#pragma unroll
      for (int rr = 0; rr < 4; ++rr)
        C[(size_t)(row + rr) * N + col] = acc[mt][nt][rr];
    }
  }
}

// ---------------- RoPE on Q and K (Q pre-scaled by log2(e)/sqrt(hd)) ----------------
__global__ void rope_qk(const float* __restrict__ qkv, ushort* __restrict__ Qb, ushort* __restrict__ Kb) {
  int idx = blockIdx.x * 256 + threadIdx.x;      // ((b*S+s)*20 + h2)*64 + i
  int i  = idx & 63;
  int t  = idx >> 6;
  int h2 = t % 20;
  int t2 = t / 20;
  int s  = t2 & (S_ - 1);
  int b  = t2 >> 11;
  float inv = exp2f(-(float)i * 0.20762050594046832f);  // log2(10000)/64
  float f = (float)s * inv;
  float sn, cs;
  sincosf(f, &sn, &cs);
  size_t row = (size_t)(b * S_ + s) * 3072;
  if (h2 < HQ_) {
    const float SCL2 = 0.12751744716705736f;   // (1/sqrt(128)) * log2(e)
    int h = h2;
    float a = qkv[row + h * 128 + i];
    float c2 = qkv[row + h * 128 + i + 64];
    size_t ob = ((size_t)((b * HQ_ + h) * S_ + s)) * 128;
    Qb[ob + i]      = f2bf((a * cs - c2 * sn) * SCL2);
    Qb[ob + i + 64] = f2bf((c2 * cs + a * sn) * SCL2);
  } else {
    int kh = h2 - HQ_;
    float a = qkv[row + 2048 + kh * 128 + i];
    float c2 = qkv[row + 2048 + kh * 128 + i + 64];
    size_t ob = ((size_t)((b * HKV_ + kh) * S_ + s)) * 128;
    Kb[ob + i]      = f2bf(a * cs - c2 * sn);
    Kb[ob + i + 64] = f2bf(c2 * cs + a * sn);
  }
}

// ---------------- V transpose: qkv f32 V-part -> Vt[b][kh][d][s-pi] bf16 ----------------
// pi permutes s within each 16-group (swap bits 2<->3) so PV's A-operand reads are single b128s.
__global__ __launch_bounds__(256) void v_transpose(const float* __restrict__ qkv, ushort* __restrict__ Vt) {
  __shared__ ushort tile[128][72];
  const int s0 = blockIdx.x * 64;
  const int kh = blockIdx.y;
  const int b  = blockIdx.z;
  for (int idx = threadIdx.x; idx < 64 * 128; idx += 256) {
    int sl = idx >> 7;
    int d  = idx & 127;
    float v = qkv[(size_t)(b * S_ + s0 + sl) * 3072 + 2560 + kh * 128 + d];
    tile[d][sl] = f2bf(v);
  }
  __syncthreads();
  for (int idx = threadIdx.x; idx < 64 * 128; idx += 256) {
    int d  = idx >> 6;
    int sl = idx & 63;
    int sp = (sl & 48) | (sl & 3) | ((sl & 8) >> 1) | ((sl & 4) << 1);  // swap bits 2,3
    Vt[((size_t)(b * HKV_ + kh) * 128 + d) * S_ + s0 + sp] = tile[d][sl];
  }
}

// ---------------- Flash attention (causal, GQA), 32x32x16 MFMA ----------------
// grid (8, HQ, B), 256 thr = 4 waves x 32 q-rows (QBLK=128). Block handles q-tiles x and 15-x
// sequentially (uniform 34 iters). KVBLK=64, double-buffered K/V staged via global_load_lds
// (linear dest + inverse-swizzled source + swizzled b128 reads).
// Swapped QK^T: sacc = K*Q^T in C-layout (col=lane&31=q) -> softmax stats lane-local, and the
// bf16-packed P is directly the B operand of O^T = V^T * P^T (k-mapping matches C rows; V is
// stored k-pi-permuted by v_transpose).
__global__ __launch_bounds__(256, 1) void attn_kernel(const ushort* __restrict__ Qb,
                                                      const ushort* __restrict__ Kb,
                                                      const ushort* __restrict__ Vt,
                                                      ushort* __restrict__ Ao) {
  __shared__ ushort Ks[2][64 * 128];
  __shared__ ushort Vs[2][128 * 64];
  const int h = blockIdx.y, b = blockIdx.z, kh = h >> 2;
  const int tid = threadIdx.x, lane = tid & 63, wave = tid >> 6;
  const int lq = lane & 31, g = lane >> 5;
  const ushort* Kg = Kb + ((size_t)(b * HKV_ + kh)) * S_ * HD_;   // [s][128]
  const ushort* Vg = Vt + ((size_t)(b * HKV_ + kh)) * HD_ * S_;   // [d][S] (k-pi within 16)

#pragma unroll 1
  for (int half = 0; half < 2; ++half) {
    const int qt = half ? (15 - (int)blockIdx.x) : (int)blockIdx.x;
    const int q0 = qt * 128;
    const int qg = q0 + wave * 32 + lq;
    const int nk = 2 * qt + 2;

    // resident Q fragments (direct global, once per q-tile)
    s16x8 qF[8];
    {
      const ushort* qrow = Qb + (((size_t)(b * HQ_ + h)) * S_ + q0 + wave * 32 + lq) * HD_ + g * 8;
#pragma unroll
      for (int s = 0; s < 8; ++s) qF[s] = *(const s16x8*)(qrow + s * 16);
    }

    // ---- stage K/V tile kt into buffer buf via global_load_lds ----
#define STAGE(buf, kt64)                                                          \
    {                                                                             \
      _Pragma("unroll")                                                           \
      for (int i_ = 0; i_ < 4; ++i_) {                                            \
        const int slot = i_ * 256 + tid;                                          \
        const int r = slot >> 4, c = slot & 15;                                   \
        const int cc = c ^ (r & 15);                                              \
        gload16(Kg + ((size_t)((kt64) * 64 + r)) * HD_ + cc * 8,                  \
                &Ks[buf][i_ * 2048 + wave * 512]);                                \
      }                                                                           \
      _Pragma("unroll")                                                           \
      for (int i_ = 0; i_ < 4; ++i_) {                                            \
        const int slot = i_ * 256 + tid;                                          \
        const int r = slot >> 3, c = slot & 7;                                    \
        const int cc = c ^ (r & 7);                                               \
        gload16(Vg + (size_t)r * S_ + (kt64) * 64 + cc * 8,                       \
                &Vs[buf][i_ * 2048 + wave * 512]);                                \
      }                                                                           \
    }

    STAGE(0, 0);

    f32x16 acc[4] = {};
    float m_run = -3.0e38f, l_run = 0.f;

    asm volatile("s_waitcnt vmcnt(0)" ::: "memory");
    __syncthreads();

    for (int kt = 0; kt < nk; ++kt) {
      const int cur = kt & 1;
      if (kt + 1 < nk) STAGE(cur ^ 1, kt + 1);
      const ushort* Kc = &Ks[cur][0];
      const ushort* Vc = &Vs[cur][0];

      // QK^T: sacc[t] = K(rows t*32..+31) x Q^T  (contraction d=128, 8 steps)
      f32x16 sacc[2];
#pragma unroll
      for (int t = 0; t < 2; ++t) {
        f32x16 a = {};
        const int row = t * 32 + lq;
#pragma unroll
        for (int s = 0; s < 8; ++s) {
          const int cc = (s * 2 + g) ^ (row & 15);
          const s16x8 kA = *(const s16x8*)(Kc + row * 128 + cc * 8);
          a = __builtin_amdgcn_mfma_f32_32x32x16_bf16(kA, qF[s], a, 0, 0, 0);
        }
        sacc[t] = a;
      }

      // softmax (log2 domain; Q pre-scaled). Lane owns q = qg; lanes l, l+32 split k.
      float tmax = -3.0e38f;
      if (kt >= 2 * qt) {   // tiles containing the diagonal
#pragma unroll
        for (int t = 0; t < 2; ++t)
#pragma unroll
          for (int r = 0; r < 16; ++r) {
            const int kg = kt * 64 + t * 32 + (r & 3) + 8 * (r >> 2) + 4 * g;
            if (kg > qg) sacc[t][r] = -3.0e38f;
            tmax = fmaxf(tmax, sacc[t][r]);
          }
      } else {
#pragma unroll
        for (int t = 0; t < 2; ++t)
#pragma unroll
          for (int r = 0; r < 16; ++r) tmax = fmaxf(tmax, sacc[t][r]);
      }
      tmax = fmaxf(tmax, __shfl_xor(tmax, 32, 64));

      if (!__all(tmax <= m_run + 8.f)) {   // defer-max (T13)
        const float m_new = fmaxf(m_run, tmax);
        const float alpha = exp2f(m_run - m_new);
        m_run = m_new;
        l_run *= alpha;
#pragma unroll
        for (int dt = 0; dt < 4; ++dt)
#pragma unroll
          for (int r = 0; r < 16; ++r) acc[dt][r] *= alpha;
      }

      float psum = 0.f;
      uint32_t pk[16];
#pragma unroll
      for (int t = 0; t < 2; ++t)
#pragma unroll
        for (int i = 0; i < 8; ++i) {
          const float e0 = exp2f(sacc[t][2 * i]     - m_run);
          const float e1 = exp2f(sacc[t][2 * i + 1] - m_run);
          psum += e0 + e1;
          asm("v_cvt_pk_bf16_f32 %0, %1, %2" : "=v"(pk[t * 8 + i]) : "v"(e0), "v"(e1));
        }
      psum += __shfl_xor(psum, 32, 64);
      l_run += psum;

      // PV: acc[dt] (O^T tile d=dt*32..+31) += V^T x P^T, 4 k-steps of 16
#pragma unroll
      for (int ks = 0; ks < 4; ++ks) {
        union { s16x8 v; uint32_t u[4]; } pb;
#pragma unroll
        for (int j = 0; j < 4; ++j) pb.u[j] = pk[ks * 4 + j];
#pragma unroll
        for (int dt = 0; dt < 4; ++dt) {
          const int row = dt * 32 + lq;
          const int cc = (ks * 2 + g) ^ (row & 7);
          const s16x8 vA = *(const s16x8*)(Vc + row * 64 + cc * 8);
          acc[dt] = __builtin_amdgcn_mfma_f32_32x32x16_bf16(vA, pb.v, acc[dt], 0, 0, 0);
        }
      }

      asm volatile("s_waitcnt vmcnt(0)" ::: "memory");
      __syncthreads();
    }

    // epilogue: O = acc / l ; d = dt*32 + (r&3) + 8*(r>>2) + 4g, q = qg
    const float inv_l = 1.f / l_run;
    ushort* orow = Ao + ((size_t)(b * S_ + qg)) * D_ + h * HD_;
#pragma unroll
    for (int dt = 0; dt < 4; ++dt)
#pragma unroll
      for (int u = 0; u < 4; ++u) {
        ushort4 w;
        w.x = f2bf(acc[dt][4 * u + 0] * inv_l);
        w.y = f2bf(acc[dt][4 * u + 1] * inv_l);
        w.z = f2bf(acc[dt][4 * u + 2] * inv_l);
        w.w = f2bf(acc[dt][4 * u + 3] * inv_l);
        *(ushort4*)(orow + dt * 32 + 8 * u + 4 * g) = w;
      }
#undef STAGE
  }
}

extern "C" void kernel_launch(void* const* d_in, const int* in_sizes, int n_in,
                              void* d_out, int out_size, void* d_ws, size_t ws_size,
                              hipStream_t stream) {
  const float* x  = (const float*)d_in[0];
  const float* wq = (const float*)d_in[1];
  const float* wk = (const float*)d_in[2];
  const float* wv = (const float*)d_in[3];
  const float* wo = (const float*)d_in[4];
  float* out = (float*)d_out;
  char* ws = (char*)d_ws;

  ushort* xb    = (ushort*)(ws);                  // 16,777,216 B
  ushort* wqkvb = (ushort*)(ws + 16777216);       // 12,582,912 B
  ushort* wob   = (ushort*)(ws + 29360128);       //  8,388,608 B
  float*  qkvf  = (float*) (ws + 37748736);       // 50,331,648 B
  ushort* Qb    = (ushort*)(ws + 88080384);       // 16,777,216 B
  ushort* Kb    = (ushort*)(ws + 104857600);      //  4,194,304 B
  ushort* Vt    = (ushort*)(ws + 109051904);      //  4,194,304 B
  ushort* Ao    = (ushort*)(ws + 113246208);      // 16,777,216 B

  cast_kernel<<<8192, 256, 0, stream>>>(x,  xb, 8388608);
  cast_kernel<<<4096, 256, 0, stream>>>(wq, wqkvb, 4194304);
  cast_kernel<<<1024, 256, 0, stream>>>(wk, wqkvb + 4194304, 1048576);
  cast_kernel<<<1024, 256, 0, stream>>>(wv, wqkvb + 5242880, 1048576);
  cast_kernel<<<4096, 256, 0, stream>>>(wo, wob, 4194304);

  gemm_nt_bf16<<<768, 256, 0, stream>>>(xb, wqkvb, qkvf, 4096, 3072, 2048, 24);
  rope_qk<<<20480, 256, 0, stream>>>(qkvf, Qb, Kb);
  v_transpose<<<dim3(32, 4, 2), 256, 0, stream>>>(qkvf, Vt);
  attn_kernel<<<dim3(8, 16, 2), 256, 0, stream>>>(Qb, Kb, Vt, Ao);
  gemm_nt_bf16<<<512, 256, 0, stream>>>(Ao, wob, out, 4096, 2048, 2048, 16);
}

// Round 4
// 332.987 us; speedup vs baseline: 1.6178x; 1.0445x over previous
//
#include <hip/hip_runtime.h>

#define B_   2
#define S_   2048
#define D_   2048
#define HQ_  16
#define HKV_ 4
#define HD_  128

typedef __attribute__((ext_vector_type(4))) float f32x4;
typedef __attribute__((ext_vector_type(16))) float f32x16;
typedef __attribute__((ext_vector_type(4))) short s16x4;
typedef __attribute__((ext_vector_type(8))) short s16x8;

static __device__ __forceinline__ ushort f2bf(float f) {
  uint32_t u = __float_as_uint(f);
  u += 0x7fffu + ((u >> 16) & 1u);   // RNE
  return (ushort)(u >> 16);
}

static __device__ __forceinline__ void gload16(const ushort* g, ushort* l) {
  __builtin_amdgcn_global_load_lds((const __attribute__((address_space(1))) uint32_t*)(g),
                                   (__attribute__((address_space(3))) uint32_t*)(l), 16, 0, 0);
}

// ---------------- fp32 -> bf16 cast ----------------
__global__ void cast_kernel(const float* __restrict__ in, ushort* __restrict__ out, int n) {
  int i = (blockIdx.x * blockDim.x + threadIdx.x) * 4;
  if (i + 3 < n) {
    float4 v = *(const float4*)(in + i);
    *(ushort4*)(out + i) = make_ushort4(f2bf(v.x), f2bf(v.y), f2bf(v.z), f2bf(v.w));
  }
}

// ---------------- GEMM: C[M][N] (f32) = A[M][K] * B[N][K]^T (both bf16 row-major) ----------------
// 128x128 tile, BK=64, m97 structure + bijective XCD swizzle (1D grid).
__global__ __launch_bounds__(256) void gemm_nt_bf16(const ushort* __restrict__ A,
                                                    const ushort* __restrict__ Bm,
                                                    float* __restrict__ C,
                                                    int M, int N, int K, int nbx) {
  __shared__ ushort As[128 * 64];
  __shared__ ushort Bs[128 * 64];
  const int nwg = gridDim.x;
  const int per = nwg >> 3;
  const int id = blockIdx.x;
  const int wg = (id & 7) * per + (id >> 3);
  const int bx = wg % nbx, by = wg / nbx;
  const int tid  = threadIdx.x;
  const int lane = tid & 63;
  const int wave = tid >> 6;
  const int lrow = lane & 15, lgrp = lane >> 4;
  const int wm = (wave >> 1) * 64, wn = (wave & 1) * 64;
  const int brow = by * 128, bcol = bx * 128;

  f32x4 acc[4][4];
#pragma unroll
  for (int i = 0; i < 4; ++i)
#pragma unroll
    for (int j = 0; j < 4; ++j) acc[i][j] = (f32x4){0.f, 0.f, 0.f, 0.f};

  const int r_ = tid >> 3, c16 = tid & 7;
  const ushort* Abase = A + (size_t)brow * K;
  const ushort* Bbase = Bm + (size_t)bcol * K;

  for (int k0 = 0; k0 < K; k0 += 64) {
#pragma unroll
    for (int q = 0; q < 4; ++q) {
      const int row = q * 32 + r_;
      const int sc = c16 ^ (row & 7);
      gload16(Abase + (size_t)row * K + k0 + sc * 8, &As[q * 2048 + wave * 512]);
      gload16(Bbase + (size_t)row * K + k0 + sc * 8, &Bs[q * 2048 + wave * 512]);
    }
    __syncthreads();
#pragma unroll
    for (int kc = 0; kc < 2; ++kc) {
      s16x8 aF[4], bF[4];
#pragma unroll
      for (int mt = 0; mt < 4; ++mt) {
        const int row = wm + mt * 16 + lrow;
        aF[mt] = *(const s16x8*)&As[row * 64 + ((kc * 32 + lgrp * 8) ^ ((row & 7) << 3))];
      }
#pragma unroll
      for (int nt = 0; nt < 4; ++nt) {
        const int row = wn + nt * 16 + lrow;
        bF[nt] = *(const s16x8*)&Bs[row * 64 + ((kc * 32 + lgrp * 8) ^ ((row & 7) << 3))];
      }
#pragma unroll
      for (int mt = 0; mt < 4; ++mt)
#pragma unroll
        for (int nt = 0; nt < 4; ++nt)
          acc[mt][nt] = __builtin_amdgcn_mfma_f32_16x16x32_bf16(aF[mt], bF[nt], acc[mt][nt], 0, 0, 0);
    }
    __syncthreads();
  }
#pragma unroll
  for (int mt = 0; mt < 4; ++mt) {
#pragma unroll
    for (int nt = 0; nt < 4; ++nt) {
      const int row = brow + wm + mt * 16 + lgrp * 4;
      const int col = bcol + wn + nt * 16 + lrow;
#pragma unroll
      for (int rr = 0; rr < 4; ++rr)
        C[(size_t)(row + rr) * N + col] = acc[mt][nt][rr];
    }
  }
}

// ---------------- RoPE on Q and K (Q pre-scaled by log2(e)/sqrt(hd)) ----------------
// One sincos per (b,s,i); loop over all 20 heads.
__global__ __launch_bounds__(256) void rope_qk(const float* __restrict__ qkv,
                                               ushort* __restrict__ Qb, ushort* __restrict__ Kb) {
  const int idx = blockIdx.x * 256 + threadIdx.x;   // (b*S+s)*64 + i
  const int i = idx & 63;
  const int t = idx >> 6;
  const int s = t & (S_ - 1);
  const int b = t >> 11;
  const float inv = exp2f(-(float)i * 0.20762050594046832f);  // log2(10000)/64
  float sn, cs;
  sincosf((float)s * inv, &sn, &cs);
  const size_t row = (size_t)t * 3072;
  const float SCL2 = 0.12751744716705736f;   // (1/sqrt(128)) * log2(e)
#pragma unroll
  for (int h = 0; h < HQ_; ++h) {
    const float a  = qkv[row + h * 128 + i];
    const float c2 = qkv[row + h * 128 + i + 64];
    const size_t ob = ((size_t)((b * HQ_ + h) * S_ + s)) * 128;
    Qb[ob + i]      = f2bf((a * cs - c2 * sn) * SCL2);
    Qb[ob + i + 64] = f2bf((c2 * cs + a * sn) * SCL2);
  }
#pragma unroll
  for (int kh = 0; kh < HKV_; ++kh) {
    const float a  = qkv[row + 2048 + kh * 128 + i];
    const float c2 = qkv[row + 2048 + kh * 128 + i + 64];
    const size_t ob = ((size_t)((b * HKV_ + kh) * S_ + s)) * 128;
    Kb[ob + i]      = f2bf(a * cs - c2 * sn);
    Kb[ob + i + 64] = f2bf(c2 * cs + a * sn);
  }
}

// ---------------- V transpose: qkv f32 V-part -> Vt[b][kh][d][s-pi] bf16 ----------------
// pi permutes s within each 16-group (swap bits 2<->3) so PV's A-operand reads are single b128s.
__global__ __launch_bounds__(256) void v_transpose(const float* __restrict__ qkv, ushort* __restrict__ Vt) {
  __shared__ ushort tile[128][72];
  const int s0 = blockIdx.x * 64;
  const int kh = blockIdx.y;
  const int b  = blockIdx.z;
  for (int idx = threadIdx.x; idx < 64 * 128; idx += 256) {
    int sl = idx >> 7;
    int d  = idx & 127;
    float v = qkv[(size_t)(b * S_ + s0 + sl) * 3072 + 2560 + kh * 128 + d];
    tile[d][sl] = f2bf(v);
  }
  __syncthreads();
  for (int idx = threadIdx.x; idx < 64 * 128; idx += 256) {
    int d  = idx >> 6;
    int sl = idx & 63;
    int sp = (sl & 48) | (sl & 3) | ((sl & 8) >> 1) | ((sl & 4) << 1);  // swap bits 2,3
    Vt[((size_t)(b * HKV_ + kh) * 128 + d) * S_ + s0 + sp] = tile[d][sl];
  }
}

// ---------------- Flash attention (causal, GQA), 32x32x16 MFMA ----------------
// grid (16, HQ, B) = 512 blocks, 256 thr = 4 waves x 32 q-rows (QBLK=128), one q-tile each.
// Mirror balance: qt = b ? 15-x : x, so block id c and c+256 (same CU under round-robin
// dispatch) carry complementary causal work -> ~34 iters per CU, 2 blocks/CU (LDS 64KB).
// KVBLK=64, double-buffered global_load_lds staging; kt-loop unrolled x2 (nk=2qt+2 even)
// so buffer-1 LDS reads fold to offset:16384 immediates; per-read addressing = 1 v_xor
// with a compile-time constant (precomputed per-lane base offsets).
__global__ __launch_bounds__(256, 2) void attn_kernel(const ushort* __restrict__ Qb,
                                                      const ushort* __restrict__ Kb,
                                                      const ushort* __restrict__ Vt,
                                                      ushort* __restrict__ Ao) {
  __shared__ ushort Ks[2][64 * 128];
  __shared__ ushort Vs[2][128 * 64];
  const int h = blockIdx.y, b = blockIdx.z, kh = h >> 2;
  const int tid = threadIdx.x, lane = tid & 63, wave = tid >> 6;
  const int lq = lane & 31, g = lane >> 5;
  const ushort* Kg = Kb + ((size_t)(b * HKV_ + kh)) * S_ * HD_;   // [s][128]
  const ushort* Vg = Vt + ((size_t)(b * HKV_ + kh)) * HD_ * S_;   // [d][S] (k-pi within 16)

  const int qt = b ? (15 - (int)blockIdx.x) : (int)blockIdx.x;
  const int q0 = qt * 128;
  const int qg = q0 + wave * 32 + lq;
  const int nk = 2 * qt + 2;

  // resident Q fragments (direct global, once)
  s16x8 qF[8];
  {
    const ushort* qrow = Qb + (((size_t)(b * HQ_ + h)) * S_ + qg) * HD_ + g * 8;
#pragma unroll
    for (int s = 0; s < 8; ++s) qF[s] = *(const s16x8*)(qrow + s * 16);
  }

  // precomputed LDS byte offsets (buffer 0); buffer 1 = +16384 (offset immediate)
  const char* KsB = (const char*)&Ks[0][0];
  const char* VsB = (const char*)&Vs[0][0];
  uint32_t ka[2], va[4];
#pragma unroll
  for (int t = 0; t < 2; ++t) ka[t] = (uint32_t)(t * 32 + lq) * 256 + ((uint32_t)(g ^ (lq & 15)) << 4);
#pragma unroll
  for (int dt = 0; dt < 4; ++dt) va[dt] = (uint32_t)(dt * 32 + lq) * 128 + ((uint32_t)(g ^ (lq & 7)) << 4);

#define STAGE(buf, kt64)                                                          \
    {                                                                             \
      _Pragma("unroll")                                                           \
      for (int i_ = 0; i_ < 4; ++i_) {                                            \
        const int slot = i_ * 256 + tid;                                          \
        const int r = slot >> 4, c = slot & 15;                                   \
        const int cc = c ^ (r & 15);                                              \
        gload16(Kg + ((size_t)((kt64) * 64 + r)) * HD_ + cc * 8,                  \
                &Ks[buf][i_ * 2048 + wave * 512]);                                \
      }                                                                           \
      _Pragma("unroll")                                                           \
      for (int i_ = 0; i_ < 4; ++i_) {                                            \
        const int slot = i_ * 256 + tid;                                          \
        const int r = slot >> 3, c = slot & 7;                                    \
        const int cc = c ^ (r & 7);                                               \
        gload16(Vg + (size_t)r * S_ + (kt64) * 64 + cc * 8,                       \
                &Vs[buf][i_ * 2048 + wave * 512]);                                \
      }                                                                           \
    }

  f32x16 acc[4] = {};
  float m_run = -3.0e38f, l_run = 0.f;

  STAGE(0, 0);
  asm volatile("s_waitcnt vmcnt(0)" ::: "memory");
  __syncthreads();

#define COMPUTE(CUR, ktv)                                                                   \
  {                                                                                         \
    f32x16 sc[2] = {};                                                                      \
    __builtin_amdgcn_s_setprio(1);                                                          \
    _Pragma("unroll")                                                                       \
    for (int s = 0; s < 8; ++s) {                                                           \
      const s16x8 k0 = *(const s16x8*)(KsB + (ka[0] ^ (uint32_t)(s << 5)) + (CUR)*16384);   \
      const s16x8 k1 = *(const s16x8*)(KsB + (ka[1] ^ (uint32_t)(s << 5)) + (CUR)*16384);   \
      sc[0] = __builtin_amdgcn_mfma_f32_32x32x16_bf16(k0, qF[s], sc[0], 0, 0, 0);           \
      sc[1] = __builtin_amdgcn_mfma_f32_32x32x16_bf16(k1, qF[s], sc[1], 0, 0, 0);           \
    }                                                                                       \
    __builtin_amdgcn_s_setprio(0);                                                          \
    float tmax = -3.0e38f;                                                                  \
    if ((ktv) >= 2 * qt) {                                                                  \
      _Pragma("unroll")                                                                     \
      for (int t = 0; t < 2; ++t)                                                           \
        _Pragma("unroll")                                                                   \
        for (int r = 0; r < 16; ++r) {                                                      \
          const int kg = (ktv) * 64 + t * 32 + (r & 3) + 8 * (r >> 2) + 4 * g;              \
          if (kg > qg) sc[t][r] = -3.0e38f;                                                 \
          tmax = fmaxf(tmax, sc[t][r]);                                                     \
        }                                                                                   \
    } else {                                                                                \
      _Pragma("unroll")                                                                     \
      for (int t = 0; t < 2; ++t)                                                           \
        _Pragma("unroll")                                                                   \
        for (int r = 0; r < 16; ++r) tmax = fmaxf(tmax, sc[t][r]);                          \
    }                                                                                       \
    tmax = fmaxf(tmax, __shfl_xor(tmax, 32, 64));                                           \
    if (!__all(tmax <= m_run + 8.f)) {                                                      \
      const float m_new = fmaxf(m_run, tmax);                                               \
      const float alpha = exp2f(m_run - m_new);                                             \
      m_run = m_new;                                                                        \
      l_run *= alpha;                                                                       \
      _Pragma("unroll")                                                                     \
      for (int dt = 0; dt < 4; ++dt)                                                        \
        _Pragma("unroll")                                                                   \
        for (int r = 0; r < 16; ++r) acc[dt][r] *= alpha;                                   \
    }                                                                                       \
    float psum = 0.f;                                                                       \
    uint32_t pk[16];                                                                        \
    _Pragma("unroll")                                                                       \
    for (int t = 0; t < 2; ++t)                                                             \
      _Pragma("unroll")                                                                     \
      for (int i = 0; i < 8; ++i) {                                                         \
        const float e0 = exp2f(sc[t][2 * i]     - m_run);                                   \
        const float e1 = exp2f(sc[t][2 * i + 1] - m_run);                                   \
        psum += e0 + e1;                                                                    \
        asm("v_cvt_pk_bf16_f32 %0, %1, %2" : "=v"(pk[t * 8 + i]) : "v"(e0), "v"(e1));       \
      }                                                                                     \
    psum += __shfl_xor(psum, 32, 64);                                                       \
    l_run += psum;                                                                          \
    __builtin_amdgcn_s_setprio(1);                                                          \
    _Pragma("unroll")                                                                       \
    for (int ks = 0; ks < 4; ++ks) {                                                        \
      union { s16x8 v; uint32_t u[4]; } pb;                                                 \
      _Pragma("unroll")                                                                     \
      for (int j = 0; j < 4; ++j) pb.u[j] = pk[ks * 4 + j];                                 \
      _Pragma("unroll")                                                                     \
      for (int dt = 0; dt < 4; ++dt) {                                                      \
        const s16x8 vA = *(const s16x8*)(VsB + (va[dt] ^ (uint32_t)(ks << 5)) + (CUR)*16384);\
        acc[dt] = __builtin_amdgcn_mfma_f32_32x32x16_bf16(vA, pb.v, acc[dt], 0, 0, 0);      \
      }                                                                                     \
    }                                                                                       \
    __builtin_amdgcn_s_setprio(0);                                                          \
  }

#pragma unroll 1
  for (int kt = 0; kt < nk; kt += 2) {
    STAGE(1, kt + 1);
    COMPUTE(0, kt);
    asm volatile("s_waitcnt vmcnt(0)" ::: "memory");
    __syncthreads();
    if (kt + 2 < nk) STAGE(0, kt + 2);
    COMPUTE(1, kt + 1);
    asm volatile("s_waitcnt vmcnt(0)" ::: "memory");
    __syncthreads();
  }

  // epilogue: O = acc / l ; d = dt*32 + (r&3) + 8*(r>>2) + 4g, q = qg
  const float inv_l = 1.f / l_run;
  ushort* orow = Ao + ((size_t)(b * S_ + qg)) * D_ + h * HD_;
#pragma unroll
  for (int dt = 0; dt < 4; ++dt)
#pragma unroll
    for (int u = 0; u < 4; ++u) {
      ushort4 w;
      w.x = f2bf(acc[dt][4 * u + 0] * inv_l);
      w.y = f2bf(acc[dt][4 * u + 1] * inv_l);
      w.z = f2bf(acc[dt][4 * u + 2] * inv_l);
      w.w = f2bf(acc[dt][4 * u + 3] * inv_l);
      *(ushort4*)(orow + dt * 32 + 8 * u + 4 * g) = w;
    }
#undef STAGE
#undef COMPUTE
}

extern "C" void kernel_launch(void* const* d_in, const int* in_sizes, int n_in,
                              void* d_out, int out_size, void* d_ws, size_t ws_size,
                              hipStream_t stream) {
  const float* x  = (const float*)d_in[0];
  const float* wq = (const float*)d_in[1];
  const float* wk = (const float*)d_in[2];
  const float* wv = (const float*)d_in[3];
  const float* wo = (const float*)d_in[4];
  float* out = (float*)d_out;
  char* ws = (char*)d_ws;

  ushort* xb    = (ushort*)(ws);                  // 16,777,216 B
  ushort* wqkvb = (ushort*)(ws + 16777216);       // 12,582,912 B
  ushort* wob   = (ushort*)(ws + 29360128);       //  8,388,608 B
  float*  qkvf  = (float*) (ws + 37748736);       // 50,331,648 B
  ushort* Qb    = (ushort*)(ws + 88080384);       // 16,777,216 B
  ushort* Kb    = (ushort*)(ws + 104857600);      //  4,194,304 B
  ushort* Vt    = (ushort*)(ws + 109051904);      //  4,194,304 B
  ushort* Ao    = (ushort*)(ws + 113246208);      // 16,777,216 B

  cast_kernel<<<8192, 256, 0, stream>>>(x,  xb, 8388608);
  cast_kernel<<<4096, 256, 0, stream>>>(wq, wqkvb, 4194304);
  cast_kernel<<<1024, 256, 0, stream>>>(wk, wqkvb + 4194304, 1048576);
  cast_kernel<<<1024, 256, 0, stream>>>(wv, wqkvb + 5242880, 1048576);
  cast_kernel<<<4096, 256, 0, stream>>>(wo, wob, 4194304);

  gemm_nt_bf16<<<768, 256, 0, stream>>>(xb, wqkvb, qkvf, 4096, 3072, 2048, 24);
  rope_qk<<<1024, 256, 0, stream>>>(qkvf, Qb, Kb);
  v_transpose<<<dim3(32, 4, 2), 256, 0, stream>>>(qkvf, Vt);
  attn_kernel<<<dim3(16, 16, 2), 256, 0, stream>>>(Qb, Kb, Vt, Ao);
  gemm_nt_bf16<<<512, 256, 0, stream>>>(Ao, wob, out, 4096, 2048, 2048, 16);
}